// Round 1
// baseline (180.921 us; speedup 1.0000x reference)
//
#include <hip/hip_runtime.h>

// LocalMean: 5x5 box filter, reflect padding, on (32,3,512,512) fp32.
// Separable: horizontal 5-sum per row (from 3 aligned float4 loads),
// vertical 5-sum via shift-register rolling over rows. Memory-bound.

constexpr int H = 512;
constexpr int W = 512;
constexpr int ROWS = 64;     // rows per block
constexpr int SUBROWS = 32;  // rows per thread (threadIdx.y splits ROWS)
constexpr int QX = W / 4;    // 128 float4 quads per row

// Horizontal 5-tap sums for one x-quad of (reflected) row yy.
__device__ __forceinline__ float4 row_hsum(const float* __restrict__ pin, int yy, int q) {
    // reflect in y: -1->1, -2->2 ; 512->510, 513->509
    if (yy < 0) yy = -yy;
    if (yy >= H) yy = 2 * H - 2 - yy;
    const float4* r = (const float4*)(pin + (size_t)yy * W);
    float4 cur = r[q];
    float pz, pw, nx, ny;
    if (q > 0) { float4 p = r[q - 1]; pz = p.z; pw = p.w; }
    else       { pz = cur.z; pw = cur.y; }   // reflect: e[-2]=e[2], e[-1]=e[1]
    if (q < QX - 1) { float4 n = r[q + 1]; nx = n.x; ny = n.y; }
    else            { nx = cur.z; ny = cur.y; } // reflect: e[512]=e[510], e[513]=e[509]
    float s = cur.x + cur.y + cur.z + cur.w;
    float4 hs;
    hs.x = (s - cur.w) + pz + pw;   // x-2..x+2
    hs.y = s + pw;                  // x-1..x+3
    hs.z = s + nx;                  // x  ..x+4
    hs.w = (s - cur.x) + nx + ny;   // x+1..x+5
    return hs;
}

__global__ __launch_bounds__(256) void localmean_kernel(const float* __restrict__ in,
                                                        float* __restrict__ out) {
    const int chunks = H / ROWS;                       // 8
    const int plane  = blockIdx.x / chunks;            // 0..95 (n*c)
    const int chunk  = blockIdx.x % chunks;
    const int y0     = chunk * ROWS + threadIdx.y * SUBROWS;
    const int q      = threadIdx.x;                    // x-quad, 0..127

    const float* pin  = in  + (size_t)plane * H * W;
    float*       pout = out + (size_t)plane * H * W;

    // warm-up: rows y0-2 .. y0+1
    float4 h0 = row_hsum(pin, y0 - 2, q);
    float4 h1 = row_hsum(pin, y0 - 1, q);
    float4 h2 = row_hsum(pin, y0,     q);
    float4 h3 = row_hsum(pin, y0 + 1, q);

    const float inv = 1.0f / 25.0f;
    #pragma unroll 4
    for (int y = y0; y < y0 + SUBROWS; ++y) {
        float4 h4 = row_hsum(pin, y + 2, q);
        float4 v;
        v.x = (h0.x + h1.x + h2.x + h3.x + h4.x) * inv;
        v.y = (h0.y + h1.y + h2.y + h3.y + h4.y) * inv;
        v.z = (h0.z + h1.z + h2.z + h3.z + h4.z) * inv;
        v.w = (h0.w + h1.w + h2.w + h3.w + h4.w) * inv;
        ((float4*)(pout + (size_t)y * W))[q] = v;
        h0 = h1; h1 = h2; h2 = h3; h3 = h4;   // shift register (renamed under unroll)
    }
}

extern "C" void kernel_launch(void* const* d_in, const int* in_sizes, int n_in,
                              void* d_out, int out_size, void* d_ws, size_t ws_size,
                              hipStream_t stream) {
    const float* in = (const float*)d_in[0];
    float* out = (float*)d_out;
    const int planes = in_sizes[0] / (H * W);          // 32*3 = 96
    dim3 grid(planes * (H / ROWS));                    // 768 blocks
    dim3 block(QX, ROWS / SUBROWS);                    // (128,2) = 256 threads
    localmean_kernel<<<grid, block, 0, stream>>>(in, out);
}